// Round 4
// baseline (125.083 us; speedup 1.0000x reference)
//
#include <hip/hip_runtime.h>

// Fused 3x3 neighborhood-attention, channel-split + LDS-reduce version.
// Block = 256 threads = 4 waves, owns 64 consecutive x-pixels of one row.
// lane = pixel (perfectly coalesced 256B per load instr); wave = channel quarter.
// Pass A: per-wave partial {sr, dot[9], ss[9]} -> LDS -> 4-way sum + softmax
// (redundant in all waves). Pass B: re-read neighbors (cache-hot), apply.
// Shapes: [b=2, c=64, h=256, w=256] fp32.

constexpr int C = 64, H = 256, W = 256, HW = H * W;
constexpr int B = 2, PIX = B * HW;
constexpr int SEG = 64;    // pixels per block
constexpr int NW  = 4;     // waves per block = channel quarters
constexpr int CG  = 16;    // channels per wave

__global__ __launch_bounds__(256) void fused_cs(const float* __restrict__ nbr,
                                                const float* __restrict__ ref,
                                                float* __restrict__ out) {
  __shared__ float part[19][NW][SEG];

  const int tid  = threadIdx.x;
  const int lane = tid & 63;
  const int w    = tid >> 6;                 // channel quarter 0..3

  const int pix = blockIdx.x * SEG + lane;   // b*HW + y*W + x  (segment never crosses a row)
  const int b   = pix >> 16;
  const int p   = pix & (HW - 1);
  const int y   = p >> 8;
  const int x   = p & (W - 1);

  // reflect padding (jnp 'reflect': -1 -> 1, H -> H-2)
  const int ym = (y == 0)     ? 1     : y - 1;
  const int yp = (y == H - 1) ? H - 2 : y + 1;
  const int xm = (x == 0)     ? 1     : x - 1;
  const int xp = (x == W - 1) ? W - 2 : x + 1;

  int off[9];
  off[0] = ym * W + xm; off[1] = ym * W + x; off[2] = ym * W + xp;
  off[3] = y  * W + xm; off[4] = y  * W + x; off[5] = y  * W + xp;
  off[6] = yp * W + xm; off[7] = yp * W + x; off[8] = yp * W + xp;
  const int ctr = y * W + x;

  const float* nb = nbr + ((size_t)b * C + w * CG) * HW;
  const float* rb = ref + ((size_t)b * C + w * CG) * HW;
  float*       ob = out + ((size_t)b * C + w * CG) * HW;

  // ---- Pass A: partial accumulations over this wave's 16 channels ----
  float sr = 0.f;
  float dot[9], ss[9];
#pragma unroll
  for (int k = 0; k < 9; ++k) { dot[k] = 0.f; ss[k] = 0.f; }

#pragma unroll 4
  for (int j = 0; j < CG; ++j) {
    const float r = rb[j * HW + ctr];
    sr = fmaf(r, r, sr);
#pragma unroll
    for (int k = 0; k < 9; ++k) {
      const float v = nb[j * HW + off[k]];   // consumed immediately: low reg pressure
      dot[k] = fmaf(r, v, dot[k]);
      ss[k]  = fmaf(v, v, ss[k]);
    }
  }

  // ---- publish partials, 4-way sum via LDS ----
  part[0][w][lane] = sr;
#pragma unroll
  for (int k = 0; k < 9; ++k) {
    part[1 + k][w][lane]  = dot[k];
    part[10 + k][w][lane] = ss[k];
  }
  __syncthreads();

  float tsr = part[0][0][lane] + part[0][1][lane] + part[0][2][lane] + part[0][3][lane];
  float td[9], tss[9];
#pragma unroll
  for (int k = 0; k < 9; ++k) {
    td[k]  = part[1 + k][0][lane] + part[1 + k][1][lane] + part[1 + k][2][lane] + part[1 + k][3][lane];
    tss[k] = part[10 + k][0][lane] + part[10 + k][1][lane] + part[10 + k][2][lane] + part[10 + k][3][lane];
  }

  // ---- normalize + softmax (redundant in all 4 waves; pure VALU, cheap) ----
  const float invr = 1.0f / fmaxf(sqrtf(tsr), 1e-12f);
  float d[9], invp[9];
  float mx = -INFINITY;
#pragma unroll
  for (int k = 0; k < 9; ++k) {
    invp[k] = 1.0f / fmaxf(sqrtf(tss[k]), 1e-12f);
    d[k]    = td[k] * invr * invp[k];
    mx      = fmaxf(mx, d[k]);
  }
  float s = 0.f;
  float coef[9];
#pragma unroll
  for (int k = 0; k < 9; ++k) {
    const float e = __expf(d[k] - mx);
    coef[k] = e;
    s += e;
  }
  const float sinv = 1.0f / s;
#pragma unroll
  for (int k = 0; k < 9; ++k) coef[k] *= sinv * invp[k];  // fold patch l2norm in

  // ---- Pass B: re-read (cache-hot), aggregate + reweight, coalesced store ----
#pragma unroll 4
  for (int j = 0; j < CG; ++j) {
    const float r = rb[j * HW + ctr];
    float a  = 0.f;
    float vc = 0.f;
#pragma unroll
    for (int k = 0; k < 9; ++k) {
      const float v = nb[j * HW + off[k]];
      a = fmaf(coef[k], v, a);
      if (k == 4) vc = v;                     // center = original nbr value
    }
    const float diff = vc - r;
    ob[j * HW + ctr] = a * __expf(-(diff * diff));   // exp(ALPHA*(nbr-ref)^2), ALPHA=-1
  }
}

extern "C" void kernel_launch(void* const* d_in, const int* in_sizes, int n_in,
                              void* d_out, int out_size, void* d_ws, size_t ws_size,
                              hipStream_t stream) {
  const float* nbr = (const float*)d_in[0];
  const float* ref = (const float*)d_in[1];
  float*       out = (float*)d_out;
  dim3 grid(PIX / SEG);   // 2048 blocks: 64 pixels each
  dim3 block(256);        // 4 waves: channel quarters
  fused_cs<<<grid, block, 0, stream>>>(nbr, ref, out);
}

// Round 5
// 47.017 us; speedup vs baseline: 2.6604x; 2.6604x over previous
//
#include <hip/hip_runtime.h>

// Fused 3x3 neighborhood-attention, single-pass register-cached version.
// Decomposition: 8 threads per pixel, each owning 8 of the 64 channels.
// Lane layout: lane = px(3 low bits) | cgroup(3 high bits) -> the 8 threads of
// one pixel are lanes {px + 8*g}; butterfly reduce over __shfl_xor 8/16/32.
// __launch_bounds__(256,3): ~170 VGPR budget so the 72-element neighbor cache
// stays in registers across the reduction (R1 was remat-limited at VGPR=64).
// Shapes: [b=2, c=64, h=256, w=256] fp32.

constexpr int C = 64, H = 256, W = 256, HW = H * W;
constexpr int CG = 8;   // channels per thread

__global__ __launch_bounds__(256, 3) void fused_nbr_attn(const float* __restrict__ nbr,
                                                         const float* __restrict__ ref,
                                                         float* __restrict__ out) {
  const int tid  = threadIdx.x;
  const int lane = tid & 63;
  const int wv   = tid >> 6;        // wave in block: 0..3
  const int px   = lane & 7;        // pixel within wave: 0..7
  const int cg   = lane >> 3;       // channel group: 0..7

  const int pix = blockIdx.x * 32 + wv * 8 + px;   // 0..131071 (b*HW + y*W + x)
  const int b   = pix >> 16;
  const int p   = pix & (HW - 1);
  const int y   = p >> 8;
  const int x   = p & (W - 1);

  // reflect padding (jnp 'reflect': -1 -> 1, H -> H-2)
  const int ym = (y == 0)     ? 1     : y - 1;
  const int yp = (y == H - 1) ? H - 2 : y + 1;
  const int xm = (x == 0)     ? 1     : x - 1;
  const int xp = (x == W - 1) ? W - 2 : x + 1;

  int off[9];
  off[0] = ym * W + xm; off[1] = ym * W + x; off[2] = ym * W + xp;
  off[3] = y  * W + xm; off[4] = y  * W + x; off[5] = y  * W + xp;
  off[6] = yp * W + xm; off[7] = yp * W + x; off[8] = yp * W + xp;
  const int ctr = y * W + x;

  const float* nb = nbr + ((size_t)b * C + cg * CG) * HW;
  const float* rb = ref + ((size_t)b * C + cg * CG) * HW;
  float*       ob = out + ((size_t)b * C + cg * CG) * HW;

  // ---- load everything once into registers (88 independent loads) ----
  float v[CG][9], r[CG];
#pragma unroll
  for (int j = 0; j < CG; ++j) {
    r[j] = rb[j * HW + ctr];
#pragma unroll
    for (int k = 0; k < 9; ++k) v[j][k] = nb[j * HW + off[k]];
  }

  // ---- partial accumulations over this thread's 8 channels ----
  float sr = 0.f;
  float dot[9], ss[9];
#pragma unroll
  for (int k = 0; k < 9; ++k) { dot[k] = 0.f; ss[k] = 0.f; }
#pragma unroll
  for (int j = 0; j < CG; ++j) {
    sr = fmaf(r[j], r[j], sr);
#pragma unroll
    for (int k = 0; k < 9; ++k) {
      dot[k] = fmaf(r[j], v[j][k], dot[k]);
      ss[k]  = fmaf(v[j][k], v[j][k], ss[k]);
    }
  }

  // ---- butterfly reduce the 19 partials across the 8 lanes of this pixel ----
#pragma unroll
  for (int m = 8; m < 64; m <<= 1) {
    sr += __shfl_xor(sr, m);
#pragma unroll
    for (int k = 0; k < 9; ++k) {
      dot[k] += __shfl_xor(dot[k], m);
      ss[k]  += __shfl_xor(ss[k], m);
    }
  }

  // ---- normalize + softmax over the 9 neighbors (redundant per lane, cheap) ----
  // inputs ~N(0,1): sums of 64 squares are O(64), never near eps -> rsqrt safe
  const float invr = __frsqrt_rn(fmaxf(sr, 1e-24f));
  float d[9], invp[9];
  float mx = -INFINITY;
#pragma unroll
  for (int k = 0; k < 9; ++k) {
    invp[k] = __frsqrt_rn(fmaxf(ss[k], 1e-24f));
    d[k]    = dot[k] * invr * invp[k];
    mx      = fmaxf(mx, d[k]);
  }
  float s = 0.f;
  float coef[9];
#pragma unroll
  for (int k = 0; k < 9; ++k) {
    const float e = __expf(d[k] - mx);
    coef[k] = e;
    s += e;
  }
  const float sinv = 1.0f / s;
#pragma unroll
  for (int k = 0; k < 9; ++k) coef[k] *= sinv * invp[k];  // fold patch l2norm in

  // ---- aggregate + elementwise reweight from registers, write out ----
#pragma unroll
  for (int j = 0; j < CG; ++j) {
    float a = 0.f;
#pragma unroll
    for (int k = 0; k < 9; ++k) a = fmaf(coef[k], v[j][k], a);
    const float diff = v[j][4] - r[j];              // center neighbor - ref
    const float wd   = __expf(-(diff * diff));      // exp(ALPHA*(nbr-ref)^2), ALPHA=-1
    ob[j * HW + ctr] = a * wd;
  }
}

extern "C" void kernel_launch(void* const* d_in, const int* in_sizes, int n_in,
                              void* d_out, int out_size, void* d_ws, size_t ws_size,
                              hipStream_t stream) {
  const float* nbr = (const float*)d_in[0];
  const float* ref = (const float*)d_in[1];
  float*       out = (float*)d_out;
  const int total_pix = 2 * HW;           // b * h * w
  dim3 grid(total_pix / 32);              // 4096 blocks: 32 pixels each
  dim3 block(256);                        // 4 waves: 8 pixels x 8 cgroups each
  fused_nbr_attn<<<grid, block, 0, stream>>>(nbr, ref, out);
}